// Round 6
// baseline (160.273 us; speedup 1.0000x reference)
//
#include <hip/hip_runtime.h>

#define BATCH 4096
#define D_IN 1024
#define D_OUT 1024
#define N_EXPERTS 8

#define TK 32
#define MAX_TILES 71        // TM=64 list bound (fallback)
#define MAX_TILES_128 39    // TM=128: 32 + 7

// ws int32 region (slots)
#define WS_PERM    0       // [4096]
#define WS_STARTS  4096    // [9]
#define WS_TILE_E  4112    // [71]
#define WS_TILE_M  4200    // [71]
#define WS_NTILES  4288    // [1]

// staged bf16 regions (byte offsets into ws)
#define WS_XHI_OFF   32768
#define WS_XLO_OFF   (32768 + 8388608)
#define WS_WHI_OFF   (32768 + 2*8388608)
#define WS_WLO_OFF   (32768 + 2*8388608 + 16777216)
#define WS_NEEDED    (32768 + 2*8388608 + 2*16777216)   // 50,364,416 B

typedef __attribute__((ext_vector_type(8))) short short8;   // 8 x bf16
typedef __attribute__((ext_vector_type(4))) float f32x4;

// fp32 -> bf16 hi/lo split (truncation; lo = next 8 mantissa bits). Unchanged.
__device__ __forceinline__ void cvt8(const float4 a, const float4 b,
                                     short8& h, short8& l) {
    float f[8] = {a.x, a.y, a.z, a.w, b.x, b.y, b.z, b.w};
#pragma unroll
    for (int i = 0; i < 8; ++i) {
        const unsigned u = __float_as_uint(f[i]);
        h[i] = (short)(u >> 16);
        const float r = f[i] - __uint_as_float(u & 0xffff0000u);
        l[i] = (short)(__float_as_uint(r) >> 16);
    }
}

// ---------------------------------------------------------------------------
// Fused prep kernel (validated R3/R4/R5). tm_tile parameterizes tile list.
// ---------------------------------------------------------------------------
__global__ __launch_bounds__(256) void prep_kernel(
    const int* __restrict__ actions, const int* __restrict__ mxs,
    const float* __restrict__ xs, const float* __restrict__ W,
    int* __restrict__ ws,
    short* __restrict__ XhiP, short* __restrict__ XloP,
    short* __restrict__ WhiP, short* __restrict__ WloP,
    float* __restrict__ out, int meta_mode, int tm_tile)
{
    const int bid = blockIdx.x;
    const int t = threadIdx.x;

    if (bid == 0) {
        __shared__ int chunkoff[64][N_EXPERTS];
        const int lane = t & 63;
        const int wave = t >> 6;

        for (int it = 0; it < 16; ++it) {
            const int c = wave * 16 + it;
            const int a = actions[c * 64 + lane];
            int myc = 0;
#pragma unroll
            for (int e = 0; e < N_EXPERTS; ++e) {
                const unsigned long long me = __ballot(a == e);
                if (lane == e) myc = (int)__popcll(me);
            }
            if (lane < N_EXPERTS) chunkoff[c][lane] = myc;
        }
        __syncthreads();

        if (wave == 0) {
            int cc0 = chunkoff[lane][0], cc1 = chunkoff[lane][1];
            int cc2 = chunkoff[lane][2], cc3 = chunkoff[lane][3];
            int cc4 = chunkoff[lane][4], cc5 = chunkoff[lane][5];
            int cc6 = chunkoff[lane][6], cc7 = chunkoff[lane][7];
            int tot0, tot1, tot2, tot3, tot4, tot5, tot6, tot7;
            int ex0, ex1, ex2, ex3, ex4, ex5, ex6, ex7;
#define SCAN1(CC, TOT, EX) do {                                   \
            int v = CC;                                           \
            _Pragma("unroll")                                     \
            for (int d = 1; d < 64; d <<= 1) {                    \
                const int u = __shfl_up(v, d, 64);                \
                if (lane >= d) v += u;                            \
            }                                                     \
            TOT = __shfl(v, 63, 64);                              \
            EX = v - CC;                                          \
        } while (0)
            SCAN1(cc0, tot0, ex0); SCAN1(cc1, tot1, ex1);
            SCAN1(cc2, tot2, ex2); SCAN1(cc3, tot3, ex3);
            SCAN1(cc4, tot4, ex4); SCAN1(cc5, tot5, ex5);
            SCAN1(cc6, tot6, ex6); SCAN1(cc7, tot7, ex7);
#undef SCAN1
            const int b0 = 0;
            const int b1 = b0 + tot0, b2 = b1 + tot1, b3 = b2 + tot2;
            const int b4 = b3 + tot3, b5 = b4 + tot4, b6 = b5 + tot5;
            const int b7 = b6 + tot6;
            chunkoff[lane][0] = b0 + ex0; chunkoff[lane][1] = b1 + ex1;
            chunkoff[lane][2] = b2 + ex2; chunkoff[lane][3] = b3 + ex3;
            chunkoff[lane][4] = b4 + ex4; chunkoff[lane][5] = b5 + ex5;
            chunkoff[lane][6] = b6 + ex6; chunkoff[lane][7] = b7 + ex7;
            if (lane == 0) {
                ws[WS_STARTS + 0] = b0; ws[WS_STARTS + 1] = b1;
                ws[WS_STARTS + 2] = b2; ws[WS_STARTS + 3] = b3;
                ws[WS_STARTS + 4] = b4; ws[WS_STARTS + 5] = b5;
                ws[WS_STARTS + 6] = b6; ws[WS_STARTS + 7] = b7;
                ws[WS_STARTS + 8] = BATCH;
                int nt = 0;
                int tots[8] = {tot0, tot1, tot2, tot3, tot4, tot5, tot6, tot7};
#pragma unroll
                for (int e = 0; e < N_EXPERTS; ++e)
                    for (int m0 = 0; m0 < tots[e]; m0 += tm_tile) {
                        ws[WS_TILE_E + nt] = e;
                        ws[WS_TILE_M + nt] = m0;
                        ++nt;
                    }
                ws[WS_NTILES] = nt;
            }
        }
        __syncthreads();

        for (int it = 0; it < 16; ++it) {
            const int c = wave * 16 + it;
            const int i = c * 64 + lane;
            const int a = actions[i];
            unsigned long long msel = 0;
#pragma unroll
            for (int e = 0; e < N_EXPERTS; ++e) {
                const unsigned long long me = __ballot(a == e);
                if (a == e) msel = me;
            }
            const int rank = (int)__popcll(msel & ((1ull << lane) - 1ull));
            const int pos = chunkoff[c][a] + rank;
            ws[WS_PERM + pos] = i;
        }
        return;
    }

    if (bid <= 16) {
        const int i = (bid - 1) * 256 + t;
        if (meta_mode == 2) {
            out[BATCH * D_OUT + i] = (float)mxs[i];
            long long* a64 = (long long*)(out + BATCH * D_OUT + BATCH);
            a64[i] = (long long)actions[i];
        } else if (meta_mode == 1) {
            out[BATCH * D_OUT + i] = (float)mxs[i];
            out[BATCH * D_OUT + BATCH + i] = (float)actions[i];
        }
        return;
    }

    const int g = (bid - 17) * 256 + t;
    if (g < 1048576) {
        // g = (((e*32+kt)*8+nt)*8 + i2)*64 + slot ; slot = j*16 + c
        const int slot = g & 63;
        const int i2   = (g >> 6) & 7;
        const int blk  = g >> 9;
        const int nt   = blk & 7;
        const int kt   = (blk >> 3) & 31;
        const int e    = blk >> 8;
        const int c    = slot & 15;
        const int j    = slot >> 4;
        const int n    = nt * 128 + i2 * 16 + c;
        const float* p = W + ((size_t)(e << 10) + n) * D_IN + kt * 32 + j * 8;
        const float4 f0 = *(const float4*)p;
        const float4 f1 = *(const float4*)(p + 4);
        short8 h, l;
        cvt8(f0, f1, h, l);
        *(short8*)(WhiP + (size_t)g * 8) = h;
        *(short8*)(WloP + (size_t)g * 8) = l;
    } else {
        const int g2 = g - 1048576;   // < 524288
        const float* p = xs + (size_t)g2 * 8;
        const float4 f0 = *(const float4*)p;
        const float4 f1 = *(const float4*)(p + 4);
        short8 h, l;
        cvt8(f0, f1, h, l);
        *(short8*)(XhiP + (size_t)g2 * 8) = h;
        *(short8*)(XloP + (size_t)g2 * 8) = l;
    }
}

// ---------------------------------------------------------------------------
// R6 GEMM: 128x128 tile, 8 waves, FOUR LDS buffers, depth-3 prefetch.
// R5 diagnosis: depth-2 pipeline gave a stage->wait window of ~1 phase
// (~400 cyc) vs ~600-900 cyc DMA latency -> ~2700 cyc stall per K-step.
// Now stage tile t+3 at phase t: window ~3 phases >> DMA latency.
// ONE barrier per K-step: "vmcnt(8) lgkmcnt(0); s_barrier".
//   - vmcnt(8): 3 stages x 4 loads in flight; oldest stage (this phase's
//     buffer) complete. Counted, never 0 in-loop (T4).
//   - lgkmcnt(0): each wave's ds_reads of buf[(t-1)%4] are serviced before
//     it passes the barrier, so staging tile t+3 into that SAME buffer
//     after the barrier cannot race an in-flight read (rule #18/#21).
// Buffers statically unrolled x4 (rule #20). LDS 129 KB -> 1 block/CU
// (grid ~312 on 256 CU was already ~1/CU).
// ---------------------------------------------------------------------------
#define TM5 128
#define TN5 128

__global__ __launch_bounds__(512) void moe_gemm_pc(
    const short* __restrict__ Xhi, const short* __restrict__ Xlo,
    const short* __restrict__ Whi, const short* __restrict__ Wlo,
    const float* __restrict__ bias, const int* __restrict__ ws,
    float* __restrict__ out)
{
    const int wid = blockIdx.x;
    const int xcd = wid & 7;
    const int j5  = wid >> 3;
    const int nsl = j5 & 7;
    const int tix = (j5 >> 3) * 8 + xcd;
    if (tix >= ws[WS_NTILES]) return;
    const int e   = ws[WS_TILE_E + tix];
    const int m0  = ws[WS_TILE_M + tix];
    const int s0  = ws[WS_STARTS + e];
    const int cnt = ws[WS_STARTS + e + 1] - s0;
    const int n0  = nsl * TN5;

    __shared__ short Ahi[4][8 * 512];   // [buf][tile(8)][slot(64)][8]  8KB each
    __shared__ short Alo[4][8 * 512];
    __shared__ short Bhi[4][8 * 512];
    __shared__ short Blo[4][8 * 512];
    __shared__ int   rows_s[TM5];

    const int t = threadIdx.x;
    if (t < TM5) {
        const int r = m0 + t;
        rows_s[t] = (r < cnt) ? ws[WS_PERM + s0 + r] : -1;
    }
    __syncthreads();

    const int lane = t & 63;
    const int wave = t >> 6;          // 0..7
    const int wm = (wave >> 1) * 32;  // quadrant m base (0,32,64,96)
    const int wn = (wave & 1) * 64;   // quadrant n base (0,64)

    const float zf = 0.f;
    f32x4 acc[2][4];
#pragma unroll
    for (int mi = 0; mi < 2; ++mi)
#pragma unroll
        for (int nj = 0; nj < 4; ++nj)
            acc[mi][nj] = (f32x4){zf, zf, zf, zf};

    // A staging: wave w stages frag tile w; lane l -> row w*16+(l&15),
    // k-octet (l>>4). Clamped row for pads (uniform 4 loads/STAGE/wave so
    // the vmcnt arithmetic is exact); pad-row acc garbage, never stored.
    const int arow0 = rows_s[wave * 16 + (lane & 15)];
    const int arow  = arow0 < 0 ? 0 : arow0;
    const short* aSrcHi = Xhi + (size_t)arow * D_IN + (lane >> 4) * 8;
    const short* aSrcLo = Xlo + (size_t)arow * D_IN + (lane >> 4) * 8;

    // B staging: staged block ((e*32+kt)*8+nsl)*4096 shorts; wave w stages
    // frag tile w (contiguous 1KB).
    const size_t wBase = ((size_t)e * 256 + (size_t)nsl) * 4096;
    const size_t bo = (size_t)wave * 512 + lane * 8;

#define STAGE(KT, BUF) do {                                                    \
        const int _kt = (KT);                                                  \
        __builtin_amdgcn_global_load_lds(                                      \
            (const __attribute__((address_space(1))) void*)(aSrcHi + _kt * 32),\
            (__attribute__((address_space(3))) void*)&Ahi[BUF][wave * 512],    \
            16, 0, 0);                                                         \
        __builtin_amdgcn_global_load_lds(                                      \
            (const __attribute__((address_space(1))) void*)(aSrcLo + _kt * 32),\
            (__attribute__((address_space(3))) void*)&Alo[BUF][wave * 512],    \
            16, 0, 0);                                                         \
        {                                                                      \
            const size_t _wo = wBase + (size_t)_kt * 32768;                    \
            __builtin_amdgcn_global_load_lds(                                  \
                (const __attribute__((address_space(1))) void*)(Whi + _wo + bo), \
                (__attribute__((address_space(3))) void*)&Bhi[BUF][wave * 512],\
                16, 0, 0);                                                     \
            __builtin_amdgcn_global_load_lds(                                  \
                (const __attribute__((address_space(1))) void*)(Wlo + _wo + bo), \
                (__attribute__((address_space(3))) void*)&Blo[BUF][wave * 512],\
                16, 0, 0);                                                     \
        }                                                                      \
    } while (0)

    const int rds = lane * 8;   // linear fragment read, conflict-free

#define FRAG_MFMA(BUF) do {                                                  \
        short8 ah[2], al[2], bh[4], bl[4];                                   \
        _Pragma("unroll")                                                    \
        for (int i2 = 0; i2 < 2; ++i2) {                                     \
            const int aoff = ((wm >> 4) + i2) * 512 + rds;                   \
            ah[i2] = *(const short8*)&Ahi[BUF][aoff];                        \
            al[i2] = *(const short8*)&Alo[BUF][aoff];                        \
        }                                                                    \
        _Pragma("unroll")                                                    \
        for (int i2 = 0; i2 < 4; ++i2) {                                     \
            const int boff = ((wn >> 4) + i2) * 512 + rds;                   \
            bh[i2] = *(const short8*)&Bhi[BUF][boff];                        \
            bl[i2] = *(const short8*)&Blo[BUF][boff];                        \
        }                                                                    \
        _Pragma("unroll")                                                    \
        for (int mi = 0; mi < 2; ++mi)                                       \
            _Pragma("unroll")                                                \
            for (int nj = 0; nj < 4; ++nj) {                                 \
                acc[mi][nj] = __builtin_amdgcn_mfma_f32_16x16x32_bf16(ah[mi], bh[nj], acc[mi][nj], 0, 0, 0); \
                acc[mi][nj] = __builtin_amdgcn_mfma_f32_16x16x32_bf16(ah[mi], bl[nj], acc[mi][nj], 0, 0, 0); \
                acc[mi][nj] = __builtin_amdgcn_mfma_f32_16x16x32_bf16(al[mi], bh[nj], acc[mi][nj], 0, 0, 0); \
            }                                                                \
    } while (0)

    // counted waits: 12 DMA in flight steady-state, oldest stage = 4 loads
#define WAIT8_BAR() asm volatile("s_waitcnt vmcnt(8) lgkmcnt(0)\n\ts_barrier" ::: "memory")
#define WAIT4_BAR() asm volatile("s_waitcnt vmcnt(4) lgkmcnt(0)\n\ts_barrier" ::: "memory")
#define WAIT0_BAR() asm volatile("s_waitcnt vmcnt(0) lgkmcnt(0)\n\ts_barrier" ::: "memory")

    // prologue: stage tiles 0,1,2 -> 12 outstanding per wave
    STAGE(0, 0);
    STAGE(1, 1);
    STAGE(2, 2);

    // phases 0..27 (7 x unroll-4): phase t waits its buf, stages tile t+3
    int kt = 3;
#pragma unroll 1
    for (int i = 0; i < 7; ++i) {
        WAIT8_BAR(); STAGE(kt,     3); FRAG_MFMA(0);
        WAIT8_BAR(); STAGE(kt + 1, 0); FRAG_MFMA(1);
        WAIT8_BAR(); STAGE(kt + 2, 1); FRAG_MFMA(2);
        WAIT8_BAR(); STAGE(kt + 3, 2); FRAG_MFMA(3);
        kt += 4;
    }
    // phase 28 (tile 28, buf0): stage last tile 31 -> buf3
    WAIT8_BAR(); STAGE(31, 3); FRAG_MFMA(0);
    // phases 29..31: drain 8 -> 4 -> 0
    WAIT8_BAR(); FRAG_MFMA(1);
    WAIT4_BAR(); FRAG_MFMA(2);
    WAIT0_BAR(); FRAG_MFMA(3);

#undef STAGE
#undef FRAG_MFMA
#undef WAIT8_BAR
#undef WAIT4_BAR
#undef WAIT0_BAR

    // Epilogue: C/D layout col=lane&15, row=(lane>>4)*4+reg
    const int cl = lane & 15;
    const int qd = lane >> 4;
    float bv[4];
#pragma unroll
    for (int nj = 0; nj < 4; ++nj)
        bv[nj] = bias[e * D_OUT + n0 + wn + nj * 16 + cl];
#pragma unroll
    for (int mi = 0; mi < 2; ++mi) {
#pragma unroll
        for (int reg = 0; reg < 4; ++reg) {
            const int mloc = wm + mi * 16 + qd * 4 + reg;
            const int r = rows_s[mloc];
            if (r >= 0) {
                float* orow = out + (size_t)r * D_OUT + n0 + wn + cl;
#pragma unroll
                for (int nj = 0; nj < 4; ++nj)
                    orow[nj * 16] = acc[mi][nj][reg] + bv[nj];
            }
        }
    }
}

// ---------------------------------------------------------------------------
// Fallback GEMM (R2, validated; TM=64 tile list): used if ws too small.
// ---------------------------------------------------------------------------
#define TMF 64
#define TNF 128

__global__ __launch_bounds__(256) void moe_gemm_fb(
    const float* __restrict__ xs, const float* __restrict__ W,
    const float* __restrict__ bias, const int* __restrict__ ws,
    float* __restrict__ out)
{
    const int tix = blockIdx.y;
    if (tix >= ws[WS_NTILES]) return;
    const int e   = ws[WS_TILE_E + tix];
    const int m0  = ws[WS_TILE_M + tix];
    const int s0  = ws[WS_STARTS + e];
    const int cnt = ws[WS_STARTS + e + 1] - s0;
    const int n0  = blockIdx.x * TNF;

    __shared__ short Ahi[2][TMF * TK];
    __shared__ short Alo[2][TMF * TK];
    __shared__ short Bhi[2][TNF * TK];
    __shared__ short Blo[2][TNF * TK];
    __shared__ int   rows_s[TMF];

    const int t = threadIdx.x;
    if (t < TMF) {
        const int r = m0 + t;
        rows_s[t] = (r < cnt) ? ws[WS_PERM + s0 + r] : -1;
    }
    __syncthreads();

    const int lane = t & 63;
    const int wave = t >> 6;
    const int wm = (wave & 1) * 32;
    const int wn = (wave >> 1) * 64;

    const float zf = 0.f;
    f32x4 acc[2][4];
#pragma unroll
    for (int mi = 0; mi < 2; ++mi)
#pragma unroll
        for (int nj = 0; nj < 4; ++nj)
            acc[mi][nj] = (f32x4){zf, zf, zf, zf};

    const float* Wb = W + (size_t)e * (D_OUT * (size_t)D_IN) + (size_t)n0 * D_IN;

    const int j  = t & 3;
    const int rr = t >> 2;

    const int arow = rows_s[rr];
    const float* aptr = (arow >= 0) ? (xs + (size_t)arow * D_IN + j * 8) : nullptr;

    const int slotA   = (j * 16 + (rr & 15)) ^ (j << 1);
    const int aoff_st = (rr >> 4) * 512 + slotA * 8;
    const int boff0   = aoff_st;
    const int boff1   = aoff_st + 4 * 512;

    const float* qb0 = Wb + (size_t)rr * D_IN + j * 8;
    const float* qb1 = Wb + (size_t)(64 + rr) * D_IN + j * 8;

    const int rds = (lane ^ ((lane >> 4) << 1)) * 8;

#define LOAD_SET(A0, A1, B0, B1, B2, B3, KOFF) do {                          \
        const int _k = (KOFF);                                               \
        if (aptr) {                                                          \
            A0 = *(const float4*)(aptr + _k);                                \
            A1 = *(const float4*)(aptr + _k + 4);                            \
        }                                                                    \
        B0 = *(const float4*)(qb0 + _k); B1 = *(const float4*)(qb0 + _k + 4);\
        B2 = *(const float4*)(qb1 + _k); B3 = *(const float4*)(qb1 + _k + 4);\
    } while (0)

#define CVT_STORE_SET(A0, A1, B0, B1, B2, B3, BUF) do {                      \
        short8 _h, _l;                                                       \
        cvt8(A0, A1, _h, _l);                                                \
        *(short8*)&Ahi[BUF][aoff_st] = _h; *(short8*)&Alo[BUF][aoff_st] = _l;\
        cvt8(B0, B1, _h, _l);                                                \
        *(short8*)&Bhi[BUF][boff0] = _h;   *(short8*)&Blo[BUF][boff0] = _l;  \
        cvt8(B2, B3, _h, _l);                                                \
        *(short8*)&Bhi[BUF][boff1] = _h;   *(short8*)&Blo[BUF][boff1] = _l;  \
    } while (0)

#define FRAG_MFMA(BUF) do {                                                  \
        short8 ah[2], al[2], bh[4], bl[4];                                   \
        _Pragma("unroll")                                                    \
        for (int i2 = 0; i2 < 2; ++i2) {                                     \
            const int aoff = ((wm >> 4) + i2) * 512 + rds;                   \
            ah[i2] = *(const short8*)&Ahi[BUF][aoff];                        \
            al[i2] = *(const short8*)&Alo[BUF][aoff];                        \
        }                                                                    \
        _Pragma("unroll")                                                    \
        for (int i2 = 0; i2 < 4; ++i2) {                                     \
            const int boff = ((wn >> 4) + i2) * 512 + rds;                   \
            bh[i2] = *(const short8*)&Bhi[BUF][boff];                        \
            bl[i2] = *(const short8*)&Blo[BUF][boff];                        \
        }                                                                    \
        _Pragma("unroll")                                                    \
        for (int mi = 0; mi < 2; ++mi)                                       \
            _Pragma("unroll")                                                \
            for (int nj = 0; nj < 4; ++nj) {                                 \
                acc[mi][nj] = __builtin_amdgcn_mfma_f32_16x16x32_bf16(ah[mi], bh[nj], acc[mi][nj], 0, 0, 0); \
                acc[mi][nj] = __builtin_amdgcn_mfma_f32_16x16x32_bf16(ah[mi], bl[nj], acc[mi][nj], 0, 0, 0); \
                acc[mi][nj] = __builtin_amdgcn_mfma_f32_16x16x32_bf16(al[mi], bh[nj], acc[mi][nj], 0, 0, 0); \
            }                                                                \
    } while (0)

#define PIPE_BARRIER() asm volatile("s_waitcnt lgkmcnt(0)\n\ts_barrier" ::: "memory")

    float4 ax0 = make_float4(0.f, 0.f, 0.f, 0.f), ax1 = ax0;
    float4 bx0, bx1, bx2, bx3;
    float4 ay0 = make_float4(0.f, 0.f, 0.f, 0.f), ay1 = ay0;
    float4 by0, by1, by2, by3;

    LOAD_SET(ax0, ax1, bx0, bx1, bx2, bx3, 0);
    CVT_STORE_SET(ax0, ax1, bx0, bx1, bx2, bx3, 0);
    LOAD_SET(ax0, ax1, bx0, bx1, bx2, bx3, TK);
    PIPE_BARRIER();

    int ke = 2 * TK;
#pragma unroll 1
    for (int i = 0; i < 15; ++i) {
        {
            LOAD_SET(ay0, ay1, by0, by1, by2, by3, ke);
            FRAG_MFMA(0);
            CVT_STORE_SET(ax0, ax1, bx0, bx1, bx2, bx3, 1);
            PIPE_BARRIER();
        }
        {
            LOAD_SET(ax0, ax1, bx0, bx1, bx2, bx3, ke + TK);
            FRAG_MFMA(1);
            CVT_STORE_SET(ay0, ay1, by0, by1, by2, by3, 0);
            PIPE_BARRIER();
        }
        ke += 2 * TK;
    }
    {
        FRAG_MFMA(0);
        CVT_STORE_SET(ax0, ax1, bx0, bx1, bx2, bx3, 1);
        PIPE_BARRIER();
    }
    {
        FRAG_MFMA(1);
    }

#undef LOAD_SET
#undef CVT_STORE_SET
#undef FRAG_MFMA
#undef PIPE_BARRIER

    const int cl = lane & 15;
    const int qd = lane >> 4;
    float bv[4];
#pragma unroll
    for (int nj = 0; nj < 4; ++nj)
        bv[nj] = bias[e * D_OUT + n0 + wn + nj * 16 + cl];
#pragma unroll
    for (int mi = 0; mi < 2; ++mi) {
#pragma unroll
        for (int reg = 0; reg < 4; ++reg) {
            const int mloc = wm + mi * 16 + qd * 4 + reg;
            const int r = rows_s[mloc];
            if (r >= 0) {
                float* orow = out + (size_t)r * D_OUT + n0 + wn + cl;
#pragma unroll
                for (int nj = 0; nj < 4; ++nj)
                    orow[nj * 16] = acc[mi][nj][reg] + bv[nj];
            }
        }
    }
}

extern "C" void kernel_launch(void* const* d_in, const int* in_sizes, int n_in,
                              void* d_out, int out_size, void* d_ws, size_t ws_size,
                              hipStream_t stream) {
    const float* xs      = (const float*)d_in[0];
    const int*   mxs     = (const int*)d_in[1];
    const int*   actions = (const int*)d_in[2];
    const float* W       = (const float*)d_in[3];
    const float* bias    = (const float*)d_in[4];
    float* out = (float*)d_out;
    int*   ws  = (int*)d_ws;
    char*  wsb = (char*)d_ws;

    short* XhiP = (short*)(wsb + WS_XHI_OFF);
    short* XloP = (short*)(wsb + WS_XLO_OFF);
    short* WhiP = (short*)(wsb + WS_WHI_OFF);
    short* WloP = (short*)(wsb + WS_WLO_OFF);

    const int metaOff = BATCH * D_OUT;
    const int meta_mode = (out_size >= metaOff + 3 * BATCH) ? 2
                        : (out_size >= metaOff + 2 * BATCH) ? 1 : 0;

    const bool big = ws_size >= (size_t)WS_NEEDED;
    const int prep_blocks = big ? (17 + 6144) : 17;
    const int tm_tile = big ? TM5 : TMF;

    prep_kernel<<<prep_blocks, 256, 0, stream>>>(
        actions, mxs, xs, W, ws, XhiP, XloP, WhiP, WloP, out, meta_mode, tm_tile);

    if (big) {
        moe_gemm_pc<<<8 * (MAX_TILES_128 + 1), 512, 0, stream>>>(
            XhiP, XloP, WhiP, WloP, bias, ws, out);
    } else {
        dim3 grid(D_OUT / TNF, MAX_TILES, 1);
        moe_gemm_fb<<<grid, 256, 0, stream>>>(xs, W, bias, ws, out);
    }
}